// Round 12
// baseline (419.750 us; speedup 1.0000x reference)
//
#include <hip/hip_runtime.h>
#include <hip/hip_bf16.h>

using bf16 = __hip_bfloat16;
typedef __attribute__((ext_vector_type(8))) __bf16 bf16x8;
typedef __attribute__((ext_vector_type(4))) float f32x4;

static __device__ __forceinline__ bf16 f2b(float v) { return __float2bfloat16(v); }
static __device__ __forceinline__ float us2f(unsigned short u) {
    return __uint_as_float(((unsigned)u) << 16);
}

// Problem: B=2, C=64, H=48, W=64, D=49, BD=98. fp32 I/O.
// MFMA pipeline, NHWC bf16. 256-thr blocks, 1 image/block, waves split pixels.
// Warp fused into conv0 staging. Large-IC LDS stages (1-4 barrier pairs/block).
// B pre-swizzled frag-order global, prefetched across steps (incl. barriers).

// ---------------------------------------------------------------------------
__global__ void sentinel_k(float* __restrict__ out, int nel, float val) {
    int i = blockIdx.x * 256 + threadIdx.x;
    if (i < nel) out[i] = val;
}

// ---------------------------------------------------------------------------
// Merged prologue: all weight packs (frag order) + feat1/feat2 NHWC transpose.
// Frag layout: o = (((t*NOCF + ocf)*NCH + cc)*64 + lane)*8 + j ; lane=q*16+m
// elem j = W[k=cc*32+q*8+j][oc=ocf*16+m] at tap t.
// ---------------------------------------------------------------------------
__global__ void prologue_k(const float* __restrict__ w0, const float* __restrict__ w1,
                           const float* __restrict__ w2, const float* __restrict__ w3,
                           const float* __restrict__ wd, const float* __restrict__ feat1,
                           const float* __restrict__ feat2, bf16* __restrict__ wsw0,
                           bf16* __restrict__ wsw0a, bf16* __restrict__ wsw1,
                           bf16* __restrict__ wsw2, bf16* __restrict__ wsw3,
                           bf16* __restrict__ wswd, bf16* __restrict__ f1n,
                           bf16* __restrict__ f2n) {
    int i = blockIdx.x * 256 + threadIdx.x;
    if (i < 110592) {
        int icbase = (i < 55296) ? 64 : 0;
        bf16* dst = (i < 55296) ? wsw0 : wsw0a;
        int o = (i < 55296) ? i : i - 55296;
        int j = o & 7, lane = (o >> 3) & 63;
        int m = lane & 15, q = lane >> 4;
        int cc = (o >> 9) & 1;
        int fragid = o >> 10;
        int t = fragid / 6, ocf = fragid % 6;
        int oc = ocf * 16 + m, ic = cc * 32 + q * 8 + j;
        dst[o] = f2b(w0[((size_t)oc * 128 + icbase + ic) * 9 + t]);
    } else if (i < 307200) {
        int o = i - 110592;
        int j = o & 7, lane = (o >> 3) & 63;
        int m = lane & 15, q = lane >> 4;
        int cc = (o >> 9) % 12;
        int fragid = (o >> 9) / 12;
        int t2 = fragid / 8, ocf = fragid % 8;
        int oc = ocf * 16 + m;
        int pc = cc * 32 + q * 8 + j;
        int dy = (t2 < 2) ? -1 : 0;
        int dx = (t2 & 1) ? 0 : -1;
        int p = pc / 96, ic = pc % 96;
        int py = p >> 1, px = p & 1;
        int ky = (dy == -1) ? (py == 1 ? 0 : -1) : (py == 0 ? 1 : 2);
        int kx = (dx == -1) ? (px == 1 ? 0 : -1) : (px == 0 ? 1 : 2);
        float v = (ky >= 0 && kx >= 0) ? w1[((size_t)oc * 96 + ic) * 9 + ky * 3 + kx] : 0.f;
        wsw1[o] = f2b(v);
    } else if (i < 454656) {
        int o = i - 307200;
        int j = o & 7, lane = (o >> 3) & 63;
        int m = lane & 15, q = lane >> 4;
        int cc = (o >> 9) % 4;
        int fragid = (o >> 9) / 4;
        int t = fragid / 8, ocf = fragid % 8;
        int oc = ocf * 16 + m, ic = cc * 32 + q * 8 + j;
        wsw2[o] = f2b(w2[((size_t)oc * 128 + ic) * 9 + t]);
    } else if (i < 528384) {
        int o = i - 454656;
        int j = o & 7, lane = (o >> 3) & 63;
        int m = lane & 15, q = lane >> 4;
        int cc = (o >> 9) % 4;
        int fragid = (o >> 9) / 4;
        int t = fragid / 4, ocf = fragid % 4;
        int oc = ocf * 16 + m, ic = cc * 32 + q * 8 + j;
        wsw3[o] = f2b(w3[((size_t)oc * 128 + ic) * 9 + t]);
    } else if (i < 561152) {
        int o = i - 528384;
        int j = o & 7, lane = (o >> 3) & 63;
        int m = lane & 15, q = lane >> 4;
        int cc = (o >> 9) & 1;
        int ocf = (o >> 10) & 1;
        int t2 = (o >> 11) & 3;
        int c = o >> 13;
        int oc = ocf * 16 + m, ic = cc * 32 + q * 8 + j;
        int qy = c >> 1, qx = c & 1;
        int dy = qy - 1 + (t2 >> 1), dx = qx - 1 + (t2 & 1);
        int ky = (qy == 0) ? (dy == -1 ? 0 : 2) : (dy == 0 ? 1 : 3);
        int kx = (qx == 0) ? (dx == -1 ? 0 : 2) : (dx == 0 ? 1 : 3);
        wswd[o] = f2b(wd[((size_t)oc * 64 + ic) * 16 + ky * 4 + kx]);
    } else if (i < 561152 + 786432) {
        int o2 = i - 561152;
        const float* src = (o2 < 393216) ? feat1 : feat2;
        bf16* dst = (o2 < 393216) ? f1n : f2n;
        int o = (o2 < 393216) ? o2 : o2 - 393216;
        int c = o & 63;
        int p = (o >> 6) % 3072;
        int b = o / (3072 * 64);
        dst[o] = f2b(src[((size_t)b * 64 + c) * 3072 + p]);
    }
}

// ---------------------------------------------------------------------------
// MFMA conv, 256 threads, 1 image/block. Waves split pixels 4-way; each wave
// computes all OC_BLK frags. A staged in LDS in ICS-channel stages (pitch
// chosen for 2-way-max conflicts); B frag-order global, prefetched one step
// ahead (including across stage barriers). WARPIN=1: conv0 with fused
// bilinear warp of f2n at coords+displacement.
// BMODE: 0 bias fp32[OCTOT]; 1 base NHWC bf16 (2,48,64,96), b=(bd0+z)/49.
// OMODE: 0 NHWC bf16+ReLU; 1 parity-pack bf16+ReLU; 4 NHWC bf16 no ReLU.
// ---------------------------------------------------------------------------
template <int IC, int ICS, int OCTOT, int OC_BLK, int H, int W, int MROWS, int NTAPS,
          int DXW, int DYLO, int DXLO, int BMODE, int OMODE, int WARPIN>
__global__ __launch_bounds__(256, 4) void conv_fz(const bf16* __restrict__ in_,
                                                  const bf16* __restrict__ wsw_,
                                                  const float* __restrict__ bias,
                                                  const bf16* __restrict__ base_,
                                                  bf16* __restrict__ out, int bd0,
                                                  const float* __restrict__ coords) {
    constexpr int NST = IC / ICS;          // LDS stages
    constexpr int ICSC = ICS / 32;         // 32-ch chunks per stage
    constexpr int KSTEPS = NTAPS * ICSC;   // MFMA steps per stage
    constexpr int TOTS = NST * KSTEPS;
    constexpr int ICS8 = ICS / 8;
    constexpr int NfT = OC_BLK / 16;
    constexpr int TPXQ = MROWS * W / 4;
    constexpr int MF = TPXQ / 16;
    constexpr int NDY = NTAPS / DXW;
    constexpr int ROWS_IN = MROWS + NDY - 1;
    constexpr int COLS_IN = W + DXW - 1;
    constexpr int NOCF = OCTOT / 16;
    constexpr int NCH = IC / 32;
    constexpr int PITCHC = ICS + 8;        // shorts per pixel (stride 2-way safe)
    constexpr int SZA = ROWS_IN * COLS_IN * PITCHC;
    constexpr int OUTSH = MROWS * W * OC_BLK;
    constexpr int SMEM = (SZA > OUTSH) ? SZA : OUTSH;
    __shared__ __align__(16) unsigned short s_mem[SMEM];

    const unsigned short* in = (const unsigned short*)in_;
    const unsigned short* wsw = (const unsigned short*)wsw_;
    const unsigned short* baseh = (const unsigned short*)base_;
    const int tid = threadIdx.x;
    const int wp = tid >> 6, lane = tid & 63;
    const int m = lane & 15, q = lane >> 4;
    const int bx = blockIdx.x, by = blockIdx.y, z = blockIdx.z;
    const int foff = m * PITCHC + q * 8;
    const int ocbase = by * OC_BLK;

    // warp-fusion per-image constants
    const int bd = bd0 + z;
    const int bimg = bd / 49;
    const int disp = bd % 49;
    const float du = (float)(disp % 7 - 3), dv = (float)(disp / 7 - 3);

    f32x4 acc[MF][NfT];
#pragma unroll
    for (int a = 0; a < MF; ++a)
#pragma unroll
        for (int nf = 0; nf < NfT; ++nf) acc[a][nf] = (f32x4){0.f, 0.f, 0.f, 0.f};

    bf16x8 bcur[NfT], bnxt[NfT];
#pragma unroll
    for (int nf = 0; nf < NfT; ++nf) {
        const int fragoc = (ocbase >> 4) + nf;
        bcur[nf] = *(const bf16x8*)(wsw + ((size_t)fragoc * NCH) * 512 + lane * 8);
    }

#pragma unroll
    for (int ss = 0; ss < NST; ++ss) {
        // ---- stage A ----
        constexpr int SZE = ROWS_IN * COLS_IN * ICS8;
        for (int i = tid; i < SZE; i += 256) {
            int e, pix;
            if constexpr ((ICS8 & (ICS8 - 1)) == 0) {
                e = i & (ICS8 - 1);
                pix = i / ICS8;
            } else {
                e = i % ICS8;
                pix = i / ICS8;
            }
            const int cI = pix % COLS_IN;
            const int rr = pix / COLS_IN;
            const int gy = bx * MROWS + rr + DYLO;
            const int gx = cI + DXLO;
            if constexpr (WARPIN) {
                // fused bilinear warp from f2n (in_) at coords + (du,dv)
                unsigned short ro[8] = {0, 0, 0, 0, 0, 0, 0, 0};
                if (gy >= 0 && gy < H && gx >= 0 && gx < W) {
                    const int p = gy * 64 + gx;
                    float cx = coords[(size_t)(bimg * 2 + 0) * 3072 + p] + du;
                    float cy = coords[(size_t)(bimg * 2 + 1) * 3072 + p] + dv;
                    float x0f = floorf(cx), y0f = floorf(cy);
                    float wx = cx - x0f, wy = cy - y0f;
                    int x0 = (int)x0f, y0 = (int)y0f;
                    int x1 = x0 + 1, y1 = y0 + 1;
                    bool vx0 = (x0 >= 0) && (x0 < 64), vx1 = (x1 >= 0) && (x1 < 64);
                    bool vy0 = (y0 >= 0) && (y0 < 48), vy1 = (y1 >= 0) && (y1 < 48);
                    int xc0 = min(max(x0, 0), 63), xc1 = min(max(x1, 0), 63);
                    int yc0 = min(max(y0, 0), 47), yc1 = min(max(y1, 0), 47);
                    float w00 = (vx0 && vy0) ? (1.f - wx) * (1.f - wy) : 0.f;
                    float w01 = (vx1 && vy0) ? wx * (1.f - wy) : 0.f;
                    float w10 = (vx0 && vy1) ? (1.f - wx) * wy : 0.f;
                    float w11 = (vx1 && vy1) ? wx * wy : 0.f;
                    const unsigned short* f2 = in + (size_t)bimg * 196608 + e * 8;
                    const uint4 ua = *(const uint4*)(f2 + (size_t)(yc0 * 64 + xc0) * 64);
                    const uint4 ub = *(const uint4*)(f2 + (size_t)(yc0 * 64 + xc1) * 64);
                    const uint4 uc = *(const uint4*)(f2 + (size_t)(yc1 * 64 + xc0) * 64);
                    const uint4 ud = *(const uint4*)(f2 + (size_t)(yc1 * 64 + xc1) * 64);
                    const unsigned short* pa = (const unsigned short*)&ua;
                    const unsigned short* pb = (const unsigned short*)&ub;
                    const unsigned short* pc = (const unsigned short*)&uc;
                    const unsigned short* pd = (const unsigned short*)&ud;
#pragma unroll
                    for (int ee = 0; ee < 8; ++ee) {
                        float v = w00 * us2f(pa[ee]) + w01 * us2f(pb[ee]) +
                                  w10 * us2f(pc[ee]) + w11 * us2f(pd[ee]);
                        bf16 r = f2b(v);
                        ro[ee] = *(unsigned short*)&r;
                    }
                }
                *(uint4*)(&s_mem[pix * PITCHC + e * 8]) = *(const uint4*)ro;
            } else {
                uint4 v = {0u, 0u, 0u, 0u};
                if (gy >= 0 && gy < H && gx >= 0 && gx < W)
                    v = *(const uint4*)(in + ((size_t)(z * H + gy) * W + gx) * IC + ss * ICS +
                                        e * 8);
                *(uint4*)(&s_mem[pix * PITCHC + e * 8]) = v;
            }
        }
        __syncthreads();
        // ---- MFMA steps ----
#pragma unroll
        for (int k = 0; k < KSTEPS; ++k) {
            const int s = ss * KSTEPS + k;
            if (s + 1 < TOTS) {
                const int sn = s + 1;
                const int ssn = sn / KSTEPS, kn = sn % KSTEPS;
                const int tn = kn / ICSC, c32n = kn % ICSC;
                const int ccgn = ssn * ICSC + c32n;
#pragma unroll
                for (int nf = 0; nf < NfT; ++nf) {
                    const int fragoc = (ocbase >> 4) + nf;
                    bnxt[nf] = *(const bf16x8*)(wsw +
                                                (((size_t)tn * NOCF + fragoc) * NCH + ccgn) * 512 +
                                                lane * 8);
                }
            }
            const int t = k / ICSC, c32 = k % ICSC;
            bf16x8 af[MF];
#pragma unroll
            for (int mf = 0; mf < MF; ++mf) {
                const int pxb = wp * TPXQ + mf * 16;
                const int yl = pxb / W, xb = pxb % W;
                const unsigned short* pa =
                    &s_mem[((yl + t / DXW) * COLS_IN + xb + t % DXW) * PITCHC + c32 * 32] + foff;
                af[mf] = *(const bf16x8*)pa;
            }
#pragma unroll
            for (int mf = 0; mf < MF; ++mf)
#pragma unroll
                for (int nf = 0; nf < NfT; ++nf)
                    acc[mf][nf] =
                        __builtin_amdgcn_mfma_f32_16x16x32_bf16(af[mf], bcur[nf], acc[mf][nf], 0, 0, 0);
            if (s + 1 < TOTS) {
#pragma unroll
                for (int nf = 0; nf < NfT; ++nf) bcur[nf] = bnxt[nf];
            }
        }
        __syncthreads();
    }

    // ---- transposed coalesced epilogue ----
    float bb[NfT];
    if constexpr (BMODE == 0) {
#pragma unroll
        for (int nf = 0; nf < NfT; ++nf) bb[nf] = bias[ocbase + nf * 16 + m];
    }
#pragma unroll
    for (int mf = 0; mf < MF; ++mf) {
        const int pxb = wp * TPXQ + mf * 16;
#pragma unroll
        for (int r = 0; r < 4; ++r) {
            const int px = pxb + q * 4 + r;
            const int yl = px / W, xl = px % W;
            const int gy = bx * MROWS + yl;
#pragma unroll
            for (int nf = 0; nf < NfT; ++nf) {
                const int oc = nf * 16 + m;
                float v = acc[mf][nf][r];
                if constexpr (BMODE == 1)
                    v += us2f(baseh[(((size_t)bimg * 48 + gy) * 64 + xl) * 96 + ocbase + oc]);
                else
                    v += bb[nf];
                if constexpr (OMODE != 4) v = fmaxf(v, 0.f);
                bf16 bv = f2b(v);
                s_mem[px * OC_BLK + oc] = *(unsigned short*)&bv;
            }
        }
    }
    __syncthreads();
    constexpr int TOT16 = MROWS * W * OC_BLK / 8;
    for (int g = tid; g < TOT16; g += 256) {
        const int o = g * 8;
        if constexpr (OMODE == 1) {
            // parity pack: MROWS==2, W==64, OC_BLK==96
            const int xx = o / 384;
            const int rr = o % 384;
            const int pp = rr / 96;
            const int oco = rr % 96;
            const int px = (pp >> 1) * 64 + 2 * xx + (pp & 1);
            uint4 vv = *(const uint4*)&s_mem[px * 96 + oco];
            *(uint4*)((unsigned short*)out + (((size_t)z * 24 + bx) * 32 + xx) * 384 + rr) = vv;
        } else {
            uint4 vv = *(const uint4*)&s_mem[o];
            const int px = o / OC_BLK;
            const int oco = o % OC_BLK;
            const int gy = bx * MROWS + px / W;
            const int xl = px % W;
            *(uint4*)((unsigned short*)out + (((size_t)z * H + gy) * W + xl) * OCTOT + ocbase +
                      oco) = vv;
        }
    }
}

// ---------------------------------------------------------------------------
// Merged 4-class deconv, 256 thr, 1 image/block, single full-IC stage.
// x3 (cnt,24,32,64) -> xd (cnt,48,64,32), ReLU. wave = parity class.
// ---------------------------------------------------------------------------
__global__ __launch_bounds__(256, 4) void deconv_c4(const bf16* __restrict__ in_,
                                                    const bf16* __restrict__ wswd_,
                                                    const float* __restrict__ bias,
                                                    bf16* __restrict__ out) {
    constexpr int PITCHC = 72;
    constexpr int SZA = 6 * 34 * PITCHC;  // 14688 shorts
    __shared__ __align__(16) unsigned short s_mem[16384];  // max(SZA, 8*64*32)

    const unsigned short* in = (const unsigned short*)in_;
    const unsigned short* wsw = (const unsigned short*)wswd_;
    const int tid = threadIdx.x;
    const int cls = tid >> 6, lane = tid & 63;
    const int m = lane & 15, q = lane >> 4;
    const int qy = cls >> 1, qx = cls & 1;
    const int bx = blockIdx.x;
    const int z = blockIdx.y;
    const int foff = m * PITCHC + q * 8;

    f32x4 acc[8][2];
#pragma unroll
    for (int a = 0; a < 8; ++a) {
        acc[a][0] = (f32x4){0.f, 0.f, 0.f, 0.f};
        acc[a][1] = (f32x4){0.f, 0.f, 0.f, 0.f};
    }

    // single stage: all 64 ic
    constexpr int SZE = 6 * 34 * 8;
    for (int i = tid; i < SZE; i += 256) {
        int e = i & 7;
        int pix = i >> 3;
        int cI = pix % 34;
        int rr = pix / 34;
        int gy = bx * 4 + rr - 1;
        int gx = cI - 1;
        uint4 v = {0u, 0u, 0u, 0u};
        if (gy >= 0 && gy < 24 && gx >= 0 && gx < 32)
            v = *(const uint4*)(in + ((size_t)(z * 24 + gy) * 32 + gx) * 64 + e * 8);
        *(uint4*)(&s_mem[pix * PITCHC + e * 8]) = v;
    }
    __syncthreads();
    {
        bf16x8 bcur[2], bnxt[2];
#pragma unroll
        for (int nf = 0; nf < 2; ++nf)
            bcur[nf] = *(const bf16x8*)(wsw + cls * 8192 + nf * 1024 + lane * 8);
#pragma unroll
        for (int s = 0; s < 8; ++s) {  // s = t*2 + cc
            if (s + 1 < 8) {
                const int tn = (s + 1) >> 1, ccn = (s + 1) & 1;
#pragma unroll
                for (int nf = 0; nf < 2; ++nf)
                    bnxt[nf] = *(const bf16x8*)(wsw + cls * 8192 + tn * 2048 + nf * 1024 +
                                                ccn * 512 + lane * 8);
            }
            const int t = s >> 1, cc = s & 1;
            const int dy = qy - 1 + (t >> 1);
            const int dx = qx - 1 + (t & 1);
            bf16x8 af[8];
#pragma unroll
            for (int mf = 0; mf < 8; ++mf) {
                const int yl = mf >> 1, xb = (mf & 1) * 16;
                const unsigned short* pa =
                    &s_mem[((yl + dy + 1) * 34 + xb + dx + 1) * PITCHC + cc * 32] + foff;
                af[mf] = *(const bf16x8*)pa;
            }
#pragma unroll
            for (int mf = 0; mf < 8; ++mf)
#pragma unroll
                for (int nf = 0; nf < 2; ++nf)
                    acc[mf][nf] =
                        __builtin_amdgcn_mfma_f32_16x16x32_bf16(af[mf], bcur[nf], acc[mf][nf], 0, 0, 0);
            if (s + 1 < 8) {
                bcur[0] = bnxt[0];
                bcur[1] = bnxt[1];
            }
        }
    }
    __syncthreads();

    const float bb0 = bias[m], bb1 = bias[16 + m];
#pragma unroll
    for (int mf = 0; mf < 8; ++mf) {
#pragma unroll
        for (int r = 0; r < 4; ++r) {
            const int px = mf * 16 + q * 4 + r;
            const int yl = px >> 5, xl = px & 31;
            const int opx = (2 * yl + qy) * 64 + 2 * xl + qx;
            float v0 = fmaxf(acc[mf][0][r] + bb0, 0.f);
            float v1 = fmaxf(acc[mf][1][r] + bb1, 0.f);
            bf16 b0 = f2b(v0), b1 = f2b(v1);
            s_mem[opx * 32 + m] = *(unsigned short*)&b0;
            s_mem[opx * 32 + 16 + m] = *(unsigned short*)&b1;
        }
    }
    __syncthreads();
    for (int g = tid; g < 2048; g += 256) {
        const int o = g * 8;
        *(uint4*)((unsigned short*)out + ((size_t)z * 3072 + bx * 512) * 32 + o) =
            *(const uint4*)&s_mem[o];
    }
}

// ---------------------------------------------------------------------------
// conv5: 3x3, 32->1, no ReLU. in NHWC bf16 (cnt,48,64,32) -> cost fp32
// ---------------------------------------------------------------------------
__global__ __launch_bounds__(256) void conv5_k(const bf16* __restrict__ in_,
                                               const float* __restrict__ w5,
                                               const float* __restrict__ b5,
                                               float* __restrict__ cost, int bd0, int cnt) {
    __shared__ float s_w5[9][32];
    const int tid = threadIdx.x;
    for (int i = tid; i < 288; i += 256) {
        int ic = i % 32, t = i / 32;
        s_w5[t][ic] = w5[ic * 9 + t];
    }
    __syncthreads();
    int idx = blockIdx.x * 256 + tid;
    if (idx >= cnt * 3072) return;
    int p = idx % 3072, z = idx / 3072;
    int y = p >> 6, x = p & 63;
    const unsigned short* in = (const unsigned short*)in_;
    float acc = b5[0];
#pragma unroll
    for (int ky = 0; ky < 3; ++ky) {
        int gy = y + ky - 1;
        if (gy < 0 || gy >= 48) continue;
#pragma unroll
        for (int kx = 0; kx < 3; ++kx) {
            int gx = x + kx - 1;
            if (gx < 0 || gx >= 64) continue;
            const ushort4* src = (const ushort4*)(in + ((size_t)(z * 48 + gy) * 64 + gx) * 32);
            const float* wr = s_w5[ky * 3 + kx];
#pragma unroll
            for (int e = 0; e < 8; ++e) {
                ushort4 u = src[e];
                acc = fmaf(us2f(u.x), wr[e * 4 + 0], acc);
                acc = fmaf(us2f(u.y), wr[e * 4 + 1], acc);
                acc = fmaf(us2f(u.z), wr[e * 4 + 2], acc);
                acc = fmaf(us2f(u.w), wr[e * 4 + 3], acc);
            }
        }
    }
    cost[(size_t)(bd0 + z) * 3072 + p] = acc;
}

// ---------------------------------------------------------------------------
// DAP (49x49) + softmax + flow expectation + coords. out fp32 (2,2,48,64)
// ---------------------------------------------------------------------------
__global__ __launch_bounds__(256) void dap_flow(const float* __restrict__ cost,
                                                const float* __restrict__ wdap,
                                                const float* __restrict__ coords,
                                                float* __restrict__ outp) {
    __shared__ float s_w[49 * 49];
    int tid = threadIdx.x;
    for (int i = tid; i < 2401; i += 256) s_w[i] = wdap[i];
    __syncthreads();
    int idx = blockIdx.x * 256 + tid;
    if (idx >= 2 * 3072) return;
    int p = idx % 3072, b = idx / 3072;
    float c[49];
#pragma unroll
    for (int d = 0; d < 49; ++d) c[d] = cost[((size_t)(b * 49 + d)) * 3072 + p];
    float mx = -1e30f;
    for (int e = 0; e < 49; ++e) {
        float s = 0.f;
#pragma unroll
        for (int d = 0; d < 49; ++d) s = fmaf(s_w[e * 49 + d], c[d], s);
        mx = fmaxf(mx, s);
    }
    float sum = 0.f, sx = 0.f, sy = 0.f;
    for (int e = 0; e < 49; ++e) {
        float s = 0.f;
#pragma unroll
        for (int d = 0; d < 49; ++d) s = fmaf(s_w[e * 49 + d], c[d], s);
        float pr = __expf(s - mx);
        sum += pr;
        sx += pr * (float)(e % 7 - 3);
        sy += pr * (float)(e / 7 - 3);
    }
    float inv = 1.f / sum;
    outp[(size_t)(b * 2 + 0) * 3072 + p] = coords[(size_t)(b * 2 + 0) * 3072 + p] + sx * inv;
    outp[(size_t)(b * 2 + 1) * 3072 + p] = coords[(size_t)(b * 2 + 1) * 3072 + p] + sy * inv;
}

// ---------------------------------------------------------------------------
extern "C" void kernel_launch(void* const* d_in, const int* in_sizes, int n_in,
                              void* d_out, int out_size, void* d_ws, size_t ws_size,
                              hipStream_t stream) {
    (void)in_sizes; (void)n_in;
    const float* feat1 = (const float*)d_in[0];
    const float* feat2 = (const float*)d_in[1];
    const float* coords = (const float*)d_in[2];
    const float* w0 = (const float*)d_in[3];
    const float* b0 = (const float*)d_in[4];
    const float* w1 = (const float*)d_in[5];
    const float* b1 = (const float*)d_in[6];
    const float* w2 = (const float*)d_in[7];
    const float* b2 = (const float*)d_in[8];
    const float* w3 = (const float*)d_in[9];
    const float* b3 = (const float*)d_in[10];
    const float* wd = (const float*)d_in[11];
    const float* bdc = (const float*)d_in[12];
    const float* w5 = (const float*)d_in[13];
    const float* b5 = (const float*)d_in[14];
    const float* wdap = (const float*)d_in[15];
    float* outp = (float*)d_out;

    // workspace (fixed):
    //  wsw0 @0 (110592) | wsw0a @110592 (110592) | wsw1 @221184 (393216)
    //  wsw2 @614400 (294912) | wsw3 @909312 (147456) | wswd @1056768 (65536)
    //  f1n @1122304 (786432) | part0(bf16) @1908736 (1179648) | cost @3088384 (1204224)
    //  f2n @4292608 (786432) | fixed_end = 5079040
    char* ws = (char*)d_ws;
    bf16* wsw0 = (bf16*)(ws + 0);
    bf16* wsw0a = (bf16*)(ws + 110592);
    bf16* wsw1 = (bf16*)(ws + 221184);
    bf16* wsw2 = (bf16*)(ws + 614400);
    bf16* wsw3 = (bf16*)(ws + 909312);
    bf16* wswd = (bf16*)(ws + 1056768);
    bf16* f1n = (bf16*)(ws + 1122304);
    bf16* part0 = (bf16*)(ws + 1908736);
    float* cost = (float*)(ws + 3088384);
    bf16* f2n = (bf16*)(ws + 4292608);
    const size_t fixed_end = 5079040;

    const int cand[7] = {98, 49, 25, 14, 7, 2, 1};
    int nb = 0;
    for (int i = 0; i < 7; ++i) {
        if (fixed_end + (size_t)983040 * cand[i] <= ws_size) { nb = cand[i]; break; }
    }
    if (nb == 0) {
        float val = 10000.f + (float)(ws_size >> 20);
        sentinel_k<<<dim3((out_size + 255) / 256), 256, 0, stream>>>(outp, out_size, val);
        return;
    }
    char* regA = ws + fixed_end;
    char* regB = regA + (size_t)393216 * nb;
    bf16* x1 = (bf16*)regA;   // (nb,24,32,128)
    bf16* x3 = (bf16*)regA;   // (nb,24,32,64)
    bf16* x0p = (bf16*)regB;  // (nb,24,32,384) parity-packed
    bf16* x2 = (bf16*)regB;   // (nb,24,32,128)
    bf16* xd = (bf16*)regB;   // (nb,48,64,32)

    // prologue: 1 merged launch + part0
    prologue_k<<<dim3(5265), 256, 0, stream>>>(w0, w1, w2, w3, wd, feat1, feat2, wsw0, wsw0a,
                                               wsw1, wsw2, wsw3, wswd, f1n, f2n);
    // part0 = conv3x3(f1n, w0[:,:64]) + b0 -> bf16 NHWC (2,48,64,96), no ReLU
    conv_fz<64, 64, 96, 96, 48, 64, 2, 9, 3, -1, -1, 0, 4, 0>
        <<<dim3(24, 1, 2), 256, 0, stream>>>(f1n, wsw0a, b0, nullptr, part0, 0, nullptr);

    for (int s = 0; s < 98; s += nb) {
        int cnt = (98 - s < nb) ? (98 - s) : nb;
        // conv0 (warp fused): IC=64 taps3x3 OC=96, base=part0, parity-pack out
        conv_fz<64, 64, 96, 96, 48, 64, 2, 9, 3, -1, -1, 1, 1, 1>
            <<<dim3(24, 1, cnt), 256, 0, stream>>>(f2n, wsw0, nullptr, part0, x0p, s, coords);
        // conv1: IC=384 (stages of 96) taps{-1,0}^2 OC=128, oc split 2
        conv_fz<384, 96, 128, 64, 24, 32, 4, 4, 2, -1, -1, 0, 0, 0>
            <<<dim3(6, 2, cnt), 256, 0, stream>>>(x0p, wsw1, b1, nullptr, x1, s, nullptr);
        // conv2: IC=128 (stages of 64) taps3x3 OC=128, oc split 2
        conv_fz<128, 64, 128, 64, 24, 32, 4, 9, 3, -1, -1, 0, 0, 0>
            <<<dim3(6, 2, cnt), 256, 0, stream>>>(x1, wsw2, b2, nullptr, x2, s, nullptr);
        // conv3: IC=128 (stages of 64) taps3x3 OC=64, no oc split
        conv_fz<128, 64, 64, 64, 24, 32, 4, 9, 3, -1, -1, 0, 0, 0>
            <<<dim3(6, 1, cnt), 256, 0, stream>>>(x2, wsw3, b3, nullptr, x3, s, nullptr);
        // deconv: merged 4 classes (wave=class), single stage
        deconv_c4<<<dim3(6, cnt), 256, 0, stream>>>(x3, wswd, bdc, xd);
        // conv5
        conv5_k<<<dim3(cnt * 12), 256, 0, stream>>>(xd, w5, b5, cost, s, cnt);
    }

    dap_flow<<<dim3(24), 256, 0, stream>>>(cost, wdap, coords, outp);
}

// Round 13
// 331.927 us; speedup vs baseline: 1.2646x; 1.2646x over previous
//
#include <hip/hip_runtime.h>
#include <hip/hip_bf16.h>

using bf16 = __hip_bfloat16;
typedef __attribute__((ext_vector_type(8))) __bf16 bf16x8;
typedef __attribute__((ext_vector_type(4))) float f32x4;

static __device__ __forceinline__ bf16 f2b(float v) { return __float2bfloat16(v); }
static __device__ __forceinline__ float us2f(unsigned short u) {
    return __uint_as_float(((unsigned)u) << 16);
}

// Problem: B=2, C=64, H=48, W=64, D=49, BD=98. fp32 I/O.
// MFMA pipeline, NHWC bf16. 256-thr blocks, 1 image/block, waves split pixels
// 4-way (each wave computes ALL oc frags). A staged in LDS per 32-ch chunk;
// B pre-swizzled frag-order global, double-buffered prefetch.
// (Round-11 conv structure — measured 370 us; round-12 warp fusion reverted.)

// ---------------------------------------------------------------------------
__global__ void sentinel_k(float* __restrict__ out, int nel, float val) {
    int i = blockIdx.x * 256 + threadIdx.x;
    if (i < nel) out[i] = val;
}

// ---------------------------------------------------------------------------
// Merged prologue: all weight packs (frag order) + feat1/feat2 NHWC transpose.
// Frag layout: o = (((t*NOCF + ocf)*NCH + cc)*64 + lane)*8 + j ; lane=q*16+m
// elem j = W[k=cc*32+q*8+j][oc=ocf*16+m] at tap t.
// ---------------------------------------------------------------------------
__global__ void prologue_k(const float* __restrict__ w0, const float* __restrict__ w1,
                           const float* __restrict__ w2, const float* __restrict__ w3,
                           const float* __restrict__ wd, const float* __restrict__ feat1,
                           const float* __restrict__ feat2, bf16* __restrict__ wsw0,
                           bf16* __restrict__ wsw0a, bf16* __restrict__ wsw1,
                           bf16* __restrict__ wsw2, bf16* __restrict__ wsw3,
                           bf16* __restrict__ wswd, bf16* __restrict__ f1n,
                           bf16* __restrict__ f2n) {
    int i = blockIdx.x * 256 + threadIdx.x;
    if (i < 110592) {
        int icbase = (i < 55296) ? 64 : 0;
        bf16* dst = (i < 55296) ? wsw0 : wsw0a;
        int o = (i < 55296) ? i : i - 55296;
        int j = o & 7, lane = (o >> 3) & 63;
        int m = lane & 15, q = lane >> 4;
        int cc = (o >> 9) & 1;
        int fragid = o >> 10;
        int t = fragid / 6, ocf = fragid % 6;
        int oc = ocf * 16 + m, ic = cc * 32 + q * 8 + j;
        dst[o] = f2b(w0[((size_t)oc * 128 + icbase + ic) * 9 + t]);
    } else if (i < 307200) {
        int o = i - 110592;
        int j = o & 7, lane = (o >> 3) & 63;
        int m = lane & 15, q = lane >> 4;
        int cc = (o >> 9) % 12;
        int fragid = (o >> 9) / 12;
        int t2 = fragid / 8, ocf = fragid % 8;
        int oc = ocf * 16 + m;
        int pc = cc * 32 + q * 8 + j;
        int dy = (t2 < 2) ? -1 : 0;
        int dx = (t2 & 1) ? 0 : -1;
        int p = pc / 96, ic = pc % 96;
        int py = p >> 1, px = p & 1;
        int ky = (dy == -1) ? (py == 1 ? 0 : -1) : (py == 0 ? 1 : 2);
        int kx = (dx == -1) ? (px == 1 ? 0 : -1) : (px == 0 ? 1 : 2);
        float v = (ky >= 0 && kx >= 0) ? w1[((size_t)oc * 96 + ic) * 9 + ky * 3 + kx] : 0.f;
        wsw1[o] = f2b(v);
    } else if (i < 454656) {
        int o = i - 307200;
        int j = o & 7, lane = (o >> 3) & 63;
        int m = lane & 15, q = lane >> 4;
        int cc = (o >> 9) % 4;
        int fragid = (o >> 9) / 4;
        int t = fragid / 8, ocf = fragid % 8;
        int oc = ocf * 16 + m, ic = cc * 32 + q * 8 + j;
        wsw2[o] = f2b(w2[((size_t)oc * 128 + ic) * 9 + t]);
    } else if (i < 528384) {
        int o = i - 454656;
        int j = o & 7, lane = (o >> 3) & 63;
        int m = lane & 15, q = lane >> 4;
        int cc = (o >> 9) % 4;
        int fragid = (o >> 9) / 4;
        int t = fragid / 4, ocf = fragid % 4;
        int oc = ocf * 16 + m, ic = cc * 32 + q * 8 + j;
        wsw3[o] = f2b(w3[((size_t)oc * 128 + ic) * 9 + t]);
    } else if (i < 561152) {
        int o = i - 528384;
        int j = o & 7, lane = (o >> 3) & 63;
        int m = lane & 15, q = lane >> 4;
        int cc = (o >> 9) & 1;
        int ocf = (o >> 10) & 1;
        int t2 = (o >> 11) & 3;
        int c = o >> 13;
        int oc = ocf * 16 + m, ic = cc * 32 + q * 8 + j;
        int qy = c >> 1, qx = c & 1;
        int dy = qy - 1 + (t2 >> 1), dx = qx - 1 + (t2 & 1);
        int ky = (qy == 0) ? (dy == -1 ? 0 : 2) : (dy == 0 ? 1 : 3);
        int kx = (qx == 0) ? (dx == -1 ? 0 : 2) : (dx == 0 ? 1 : 3);
        wswd[o] = f2b(wd[((size_t)oc * 64 + ic) * 16 + ky * 4 + kx]);
    } else if (i < 561152 + 786432) {
        int o2 = i - 561152;
        const float* src = (o2 < 393216) ? feat1 : feat2;
        bf16* dst = (o2 < 393216) ? f1n : f2n;
        int o = (o2 < 393216) ? o2 : o2 - 393216;
        int c = o & 63;
        int p = (o >> 6) % 3072;
        int b = o / (3072 * 64);
        dst[o] = f2b(src[((size_t)b * 64 + c) * 3072 + p]);
    }
}

// ---------------------------------------------------------------------------
// warp: bilinear from f2n (NHWC bf16). thread = (pixel, 8-channel group), 16B.
// ---------------------------------------------------------------------------
__global__ __launch_bounds__(256) void warp_kernel(const bf16* __restrict__ f2n,
                                                   const float* __restrict__ coords,
                                                   bf16* __restrict__ f2w, int bd0, int cnt) {
    int idx = blockIdx.x * 256 + threadIdx.x;
    if (idx >= cnt * 3072 * 8) return;
    int g = idx & 7;
    int pix = idx >> 3;
    int p = pix % 3072;
    int z = pix / 3072;
    int bd = bd0 + z;
    int b = bd / 49, d = bd % 49;
    float du = (float)(d % 7 - 3), dv = (float)(d / 7 - 3);
    float cx = coords[(size_t)(b * 2 + 0) * 3072 + p] + du;
    float cy = coords[(size_t)(b * 2 + 1) * 3072 + p] + dv;
    float x0f = floorf(cx), y0f = floorf(cy);
    float wx = cx - x0f, wy = cy - y0f;
    int x0 = (int)x0f, y0 = (int)y0f;
    int x1 = x0 + 1, y1 = y0 + 1;
    bool vx0 = (x0 >= 0) && (x0 < 64), vx1 = (x1 >= 0) && (x1 < 64);
    bool vy0 = (y0 >= 0) && (y0 < 48), vy1 = (y1 >= 0) && (y1 < 48);
    int xc0 = min(max(x0, 0), 63), xc1 = min(max(x1, 0), 63);
    int yc0 = min(max(y0, 0), 47), yc1 = min(max(y1, 0), 47);
    float w00 = (vx0 && vy0) ? (1.f - wx) * (1.f - wy) : 0.f;
    float w01 = (vx1 && vy0) ? wx * (1.f - wy) : 0.f;
    float w10 = (vx0 && vy1) ? (1.f - wx) * wy : 0.f;
    float w11 = (vx1 && vy1) ? wx * wy : 0.f;
    const unsigned short* f2 = (const unsigned short*)f2n + (size_t)b * 3072 * 64 + g * 8;
    ushort4 a0 = *(const ushort4*)(f2 + (size_t)(yc0 * 64 + xc0) * 64);
    ushort4 a1 = *(const ushort4*)(f2 + (size_t)(yc0 * 64 + xc0) * 64 + 4);
    ushort4 b0v = *(const ushort4*)(f2 + (size_t)(yc0 * 64 + xc1) * 64);
    ushort4 b1v = *(const ushort4*)(f2 + (size_t)(yc0 * 64 + xc1) * 64 + 4);
    ushort4 c0 = *(const ushort4*)(f2 + (size_t)(yc1 * 64 + xc0) * 64);
    ushort4 c1 = *(const ushort4*)(f2 + (size_t)(yc1 * 64 + xc0) * 64 + 4);
    ushort4 d0 = *(const ushort4*)(f2 + (size_t)(yc1 * 64 + xc1) * 64);
    ushort4 d1 = *(const ushort4*)(f2 + (size_t)(yc1 * 64 + xc1) * 64 + 4);
    unsigned short ua[8] = {a0.x, a0.y, a0.z, a0.w, a1.x, a1.y, a1.z, a1.w};
    unsigned short ub[8] = {b0v.x, b0v.y, b0v.z, b0v.w, b1v.x, b1v.y, b1v.z, b1v.w};
    unsigned short uc[8] = {c0.x, c0.y, c0.z, c0.w, c1.x, c1.y, c1.z, c1.w};
    unsigned short ud[8] = {d0.x, d0.y, d0.z, d0.w, d1.x, d1.y, d1.z, d1.w};
    unsigned short ro[8];
#pragma unroll
    for (int e = 0; e < 8; ++e) {
        float v = w00 * us2f(ua[e]) + w01 * us2f(ub[e]) + w10 * us2f(uc[e]) + w11 * us2f(ud[e]);
        bf16 r = f2b(v);
        ro[e] = *(unsigned short*)&r;
    }
    unsigned short* outp = (unsigned short*)f2w + ((size_t)z * 3072 + p) * 64 + g * 8;
    *(ushort4*)outp = (ushort4){ro[0], ro[1], ro[2], ro[3]};
    *(ushort4*)(outp + 4) = (ushort4){ro[4], ro[5], ro[6], ro[7]};
}

// ---------------------------------------------------------------------------
// 256-thread MFMA conv, 1 image/block. Waves split PIXELS 4-way; each wave
// computes all OC_BLK frags (NfT = OC_BLK/16) -> A ds_read per MFMA halved.
// A staged in LDS (uint4); B frag-order global double-buffered.
// BMODE: 0 bias fp32[OCTOT]; 1 base NHWC bf16 (2,48,64,96), b=(bd0+z)/49.
// OMODE: 0 NHWC bf16+ReLU (transposed); 1 parity-pack (transposed);
//        4 NHWC bf16 NO ReLU (transposed).
// ---------------------------------------------------------------------------
template <int IC, int OCTOT, int OC_BLK, int H, int W, int MROWS, int NTAPS, int DXW,
          int DYLO, int DXLO, int BMODE, int OMODE>
__global__ __launch_bounds__(256, 4) void conv_px4(const bf16* __restrict__ in_,
                                                   const bf16* __restrict__ wsw_,
                                                   const float* __restrict__ bias,
                                                   const bf16* __restrict__ base_,
                                                   bf16* __restrict__ out, int bd0) {
    constexpr int NCH = IC / 32;
    constexpr int NfT = OC_BLK / 16;      // all oc frags per wave
    constexpr int TPXQ = MROWS * W / 4;   // px per wave
    constexpr int MF = TPXQ / 16;         // A frags per wave
    constexpr int NDY = NTAPS / DXW;
    constexpr int ROWS_IN = MROWS + NDY - 1;
    constexpr int COLS_IN = W + DXW - 1;
    constexpr int NOCF = OCTOT / 16;
    constexpr int PITCH = 40;
    constexpr int SZA = ROWS_IN * COLS_IN * PITCH;
    constexpr int OUTSH = MROWS * W * OC_BLK;
    constexpr int SMEM = (SZA > OUTSH) ? SZA : OUTSH;
    __shared__ __align__(16) unsigned short s_mem[SMEM];

    const unsigned short* in = (const unsigned short*)in_;
    const unsigned short* wsw = (const unsigned short*)wsw_;
    const unsigned short* baseh = (const unsigned short*)base_;
    const int tid = threadIdx.x;
    const int wp = tid >> 6, lane = tid & 63;
    const int m = lane & 15, q = lane >> 4;
    const int bx = blockIdx.x, by = blockIdx.y, z = blockIdx.z;
    const int foff = m * PITCH + q * 8;
    const int ocbase = by * OC_BLK;

    f32x4 acc[MF][NfT];
#pragma unroll
    for (int a = 0; a < MF; ++a)
#pragma unroll
        for (int nf = 0; nf < NfT; ++nf) acc[a][nf] = (f32x4){0.f, 0.f, 0.f, 0.f};

    for (int cc = 0; cc < NCH; ++cc) {
        constexpr int SZE = ROWS_IN * COLS_IN * 4;  // uint4 units
        for (int i = tid; i < SZE; i += 256) {
            int e = i & 3;
            int pix = i >> 2;
            int cI = pix % COLS_IN;
            int rr = pix / COLS_IN;
            int gy = bx * MROWS + rr + DYLO;
            int gx = cI + DXLO;
            uint4 v = {0u, 0u, 0u, 0u};
            if (gy >= 0 && gy < H && gx >= 0 && gx < W)
                v = *(const uint4*)(in + ((size_t)(z * H + gy) * W + gx) * IC + cc * 32 + e * 8);
            *(uint4*)(&s_mem[pix * PITCH + e * 8]) = v;
        }
        __syncthreads();
        {
            bf16x8 bcur[NfT], bnxt[NfT];
#pragma unroll
            for (int nf = 0; nf < NfT; ++nf) {
                const int fragoc = (ocbase >> 4) + nf;
                bcur[nf] = *(const bf16x8*)(wsw + (((size_t)0 * NOCF + fragoc) * NCH + cc) * 512 +
                                            lane * 8);
            }
#pragma unroll
            for (int t = 0; t < NTAPS; ++t) {
                if (t + 1 < NTAPS) {
#pragma unroll
                    for (int nf = 0; nf < NfT; ++nf) {
                        const int fragoc = (ocbase >> 4) + nf;
                        bnxt[nf] = *(const bf16x8*)(wsw +
                                                    (((size_t)(t + 1) * NOCF + fragoc) * NCH + cc) *
                                                        512 +
                                                    lane * 8);
                    }
                }
                bf16x8 af[MF];
#pragma unroll
                for (int mf = 0; mf < MF; ++mf) {
                    const int pxb = wp * TPXQ + mf * 16;
                    const int yl = pxb / W, xb = pxb % W;
                    const unsigned short* pa =
                        &s_mem[((yl + t / DXW) * COLS_IN + xb + t % DXW) * PITCH] + foff;
                    af[mf] = *(const bf16x8*)pa;
                }
#pragma unroll
                for (int mf = 0; mf < MF; ++mf)
#pragma unroll
                    for (int nf = 0; nf < NfT; ++nf)
                        acc[mf][nf] = __builtin_amdgcn_mfma_f32_16x16x32_bf16(af[mf], bcur[nf],
                                                                              acc[mf][nf], 0, 0, 0);
                if (t + 1 < NTAPS) {
#pragma unroll
                    for (int nf = 0; nf < NfT; ++nf) bcur[nf] = bnxt[nf];
                }
            }
        }
        __syncthreads();
    }

    // transposed coalesced epilogue (all waves write disjoint px ranges)
    const int bimg = (bd0 + z) / 49;
    float bb[NfT];
    if constexpr (BMODE == 0) {
#pragma unroll
        for (int nf = 0; nf < NfT; ++nf) bb[nf] = bias[ocbase + nf * 16 + m];
    }
#pragma unroll
    for (int mf = 0; mf < MF; ++mf) {
        const int pxb = wp * TPXQ + mf * 16;
#pragma unroll
        for (int r = 0; r < 4; ++r) {
            const int px = pxb + q * 4 + r;
            const int yl = px / W, xl = px % W;
            const int gy = bx * MROWS + yl;
#pragma unroll
            for (int nf = 0; nf < NfT; ++nf) {
                const int oc = nf * 16 + m;
                float v = acc[mf][nf][r];
                if constexpr (BMODE == 1)
                    v += us2f(baseh[(((size_t)bimg * 48 + gy) * 64 + xl) * 96 + ocbase + oc]);
                else
                    v += bb[nf];
                if constexpr (OMODE != 4) v = fmaxf(v, 0.f);
                bf16 bv = f2b(v);
                s_mem[px * OC_BLK + oc] = *(unsigned short*)&bv;
            }
        }
    }
    __syncthreads();
    constexpr int TOT16 = MROWS * W * OC_BLK / 8;
    for (int g = tid; g < TOT16; g += 256) {
        const int o = g * 8;
        if constexpr (OMODE == 1) {
            // parity pack: MROWS==2, W==64, OC_BLK==96
            const int xx = o / 384;
            const int rr = o % 384;
            const int pp = rr / 96;
            const int oco = rr % 96;
            const int px = (pp >> 1) * 64 + 2 * xx + (pp & 1);
            uint4 vv = *(const uint4*)&s_mem[px * 96 + oco];
            *(uint4*)((unsigned short*)out + (((size_t)z * 24 + bx) * 32 + xx) * 384 + rr) = vv;
        } else {
            uint4 vv = *(const uint4*)&s_mem[o];
            const int px = o / OC_BLK;
            const int oco = o % OC_BLK;
            const int gy = bx * MROWS + px / W;
            const int xl = px % W;
            *(uint4*)((unsigned short*)out + (((size_t)z * H + gy) * W + xl) * OCTOT + ocbase +
                      oco) = vv;
        }
    }
}

// ---------------------------------------------------------------------------
// Merged 4-class deconv, 256 thr, 1 image/block. wave = parity class.
// x3 (cnt,24,32,64) -> xd (cnt,48,64,32), ReLU.
// ---------------------------------------------------------------------------
__global__ __launch_bounds__(256, 4) void deconv_c4(const bf16* __restrict__ in_,
                                                    const bf16* __restrict__ wswd_,
                                                    const float* __restrict__ bias,
                                                    bf16* __restrict__ out) {
    constexpr int PITCH = 40;
    __shared__ __align__(16) unsigned short s_mem[16384];  // max(6*34*40, 8*64*32)

    const unsigned short* in = (const unsigned short*)in_;
    const unsigned short* wsw = (const unsigned short*)wswd_;
    const int tid = threadIdx.x;
    const int cls = tid >> 6, lane = tid & 63;
    const int m = lane & 15, q = lane >> 4;
    const int qy = cls >> 1, qx = cls & 1;
    const int bx = blockIdx.x;
    const int z = blockIdx.y;
    const int foff = m * PITCH + q * 8;

    f32x4 acc[8][2];
#pragma unroll
    for (int a = 0; a < 8; ++a) {
        acc[a][0] = (f32x4){0.f, 0.f, 0.f, 0.f};
        acc[a][1] = (f32x4){0.f, 0.f, 0.f, 0.f};
    }

    for (int cc = 0; cc < 2; ++cc) {
        constexpr int SZE = 6 * 34 * 4;
        for (int i = tid; i < SZE; i += 256) {
            int e = i & 3;
            int pix = i >> 2;
            int cI = pix % 34;
            int rr = pix / 34;
            int gy = bx * 4 + rr - 1;
            int gx = cI - 1;
            uint4 v = {0u, 0u, 0u, 0u};
            if (gy >= 0 && gy < 24 && gx >= 0 && gx < 32)
                v = *(const uint4*)(in + ((size_t)(z * 24 + gy) * 32 + gx) * 64 + cc * 32 + e * 8);
            *(uint4*)(&s_mem[pix * PITCH + e * 8]) = v;
        }
        __syncthreads();
        {
            bf16x8 bcur[2], bnxt[2];
#pragma unroll
            for (int nf = 0; nf < 2; ++nf)
                bcur[nf] = *(const bf16x8*)(wsw + cls * 8192 + nf * 1024 + cc * 512 + lane * 8);
#pragma unroll
            for (int t = 0; t < 4; ++t) {
                if (t + 1 < 4) {
#pragma unroll
                    for (int nf = 0; nf < 2; ++nf)
                        bnxt[nf] = *(const bf16x8*)(wsw + cls * 8192 + (t + 1) * 2048 + nf * 1024 +
                                                    cc * 512 + lane * 8);
                }
                const int dy = qy - 1 + (t >> 1);
                const int dx = qx - 1 + (t & 1);
                bf16x8 af[8];
#pragma unroll
                for (int mf = 0; mf < 8; ++mf) {
                    const int yl = mf >> 1, xb = (mf & 1) * 16;
                    const unsigned short* pa =
                        &s_mem[((yl + dy + 1) * 34 + xb + dx + 1) * PITCH] + foff;
                    af[mf] = *(const bf16x8*)pa;
                }
#pragma unroll
                for (int mf = 0; mf < 8; ++mf)
#pragma unroll
                    for (int nf = 0; nf < 2; ++nf)
                        acc[mf][nf] = __builtin_amdgcn_mfma_f32_16x16x32_bf16(af[mf], bcur[nf],
                                                                              acc[mf][nf], 0, 0, 0);
                if (t + 1 < 4) {
                    bcur[0] = bnxt[0];
                    bcur[1] = bnxt[1];
                }
            }
        }
        __syncthreads();
    }

    const float bb0 = bias[m], bb1 = bias[16 + m];
#pragma unroll
    for (int mf = 0; mf < 8; ++mf) {
#pragma unroll
        for (int r = 0; r < 4; ++r) {
            const int px = mf * 16 + q * 4 + r;
            const int yl = px >> 5, xl = px & 31;
            const int opx = (2 * yl + qy) * 64 + 2 * xl + qx;
            float v0 = fmaxf(acc[mf][0][r] + bb0, 0.f);
            float v1 = fmaxf(acc[mf][1][r] + bb1, 0.f);
            bf16 b0 = f2b(v0), b1 = f2b(v1);
            s_mem[opx * 32 + m] = *(unsigned short*)&b0;
            s_mem[opx * 32 + 16 + m] = *(unsigned short*)&b1;
        }
    }
    __syncthreads();
    for (int g = tid; g < 2048; g += 256) {
        const int o = g * 8;
        *(uint4*)((unsigned short*)out + ((size_t)z * 3072 + bx * 512) * 32 + o) =
            *(const uint4*)&s_mem[o];
    }
}

// ---------------------------------------------------------------------------
// conv5: 3x3, 32->1, no ReLU. in NHWC bf16 (cnt,48,64,32) -> cost fp32
// ---------------------------------------------------------------------------
__global__ __launch_bounds__(256) void conv5_k(const bf16* __restrict__ in_,
                                               const float* __restrict__ w5,
                                               const float* __restrict__ b5,
                                               float* __restrict__ cost, int bd0, int cnt) {
    __shared__ float s_w5[9][32];
    const int tid = threadIdx.x;
    for (int i = tid; i < 288; i += 256) {
        int ic = i % 32, t = i / 32;
        s_w5[t][ic] = w5[ic * 9 + t];
    }
    __syncthreads();
    int idx = blockIdx.x * 256 + tid;
    if (idx >= cnt * 3072) return;
    int p = idx % 3072, z = idx / 3072;
    int y = p >> 6, x = p & 63;
    const unsigned short* in = (const unsigned short*)in_;
    float acc = b5[0];
#pragma unroll
    for (int ky = 0; ky < 3; ++ky) {
        int gy = y + ky - 1;
        if (gy < 0 || gy >= 48) continue;
#pragma unroll
        for (int kx = 0; kx < 3; ++kx) {
            int gx = x + kx - 1;
            if (gx < 0 || gx >= 64) continue;
            const ushort4* src = (const ushort4*)(in + ((size_t)(z * 48 + gy) * 64 + gx) * 32);
            const float* wr = s_w5[ky * 3 + kx];
#pragma unroll
            for (int e = 0; e < 8; ++e) {
                ushort4 u = src[e];
                acc = fmaf(us2f(u.x), wr[e * 4 + 0], acc);
                acc = fmaf(us2f(u.y), wr[e * 4 + 1], acc);
                acc = fmaf(us2f(u.z), wr[e * 4 + 2], acc);
                acc = fmaf(us2f(u.w), wr[e * 4 + 3], acc);
            }
        }
    }
    cost[(size_t)(bd0 + z) * 3072 + p] = acc;
}

// ---------------------------------------------------------------------------
// Waveized DAP+softmax+flow: one wave per pixel. Lane e<49 holds score s_e in
// a register (single pass); shuffle-reduce max/sum/sx/sy. out fp32 (2,2,48,64)
// ---------------------------------------------------------------------------
__global__ __launch_bounds__(256) void dap_flow_w(const float* __restrict__ cost,
                                                  const float* __restrict__ wdap,
                                                  const float* __restrict__ coords,
                                                  float* __restrict__ outp) {
    __shared__ float s_w[2401];
    __shared__ float s_c[4][52];
    const int tid = threadIdx.x;
    const int w = tid >> 6, lane = tid & 63;
    const int idx = blockIdx.x * 4 + w;
    const int p = idx % 3072, b = idx / 3072;
    for (int i = tid; i < 2401; i += 256) s_w[i] = wdap[i];
    if (lane < 49) s_c[w][lane] = cost[((size_t)(b * 49 + lane)) * 3072 + p];
    __syncthreads();
    float s = -1e30f;
    if (lane < 49) {
        s = 0.f;
        const float* wr = &s_w[lane * 49];
        const float* cr = s_c[w];
#pragma unroll
        for (int d = 0; d < 49; ++d) s = fmaf(wr[d], cr[d], s);
    }
    float mx = s;
#pragma unroll
    for (int off = 32; off; off >>= 1) mx = fmaxf(mx, __shfl_xor(mx, off));
    float pr = (lane < 49) ? __expf(s - mx) : 0.f;
    float sum = pr;
    float sx = pr * (float)(lane % 7 - 3);
    float sy = pr * (float)(lane / 7 - 3);
#pragma unroll
    for (int off = 32; off; off >>= 1) {
        sum += __shfl_xor(sum, off);
        sx += __shfl_xor(sx, off);
        sy += __shfl_xor(sy, off);
    }
    if (lane == 0) {
        float inv = 1.f / sum;
        outp[(size_t)(b * 2 + 0) * 3072 + p] = coords[(size_t)(b * 2 + 0) * 3072 + p] + sx * inv;
        outp[(size_t)(b * 2 + 1) * 3072 + p] = coords[(size_t)(b * 2 + 1) * 3072 + p] + sy * inv;
    }
}

// ---------------------------------------------------------------------------
extern "C" void kernel_launch(void* const* d_in, const int* in_sizes, int n_in,
                              void* d_out, int out_size, void* d_ws, size_t ws_size,
                              hipStream_t stream) {
    (void)in_sizes; (void)n_in;
    const float* feat1 = (const float*)d_in[0];
    const float* feat2 = (const float*)d_in[1];
    const float* coords = (const float*)d_in[2];
    const float* w0 = (const float*)d_in[3];
    const float* b0 = (const float*)d_in[4];
    const float* w1 = (const float*)d_in[5];
    const float* b1 = (const float*)d_in[6];
    const float* w2 = (const float*)d_in[7];
    const float* b2 = (const float*)d_in[8];
    const float* w3 = (const float*)d_in[9];
    const float* b3 = (const float*)d_in[10];
    const float* wd = (const float*)d_in[11];
    const float* bdc = (const float*)d_in[12];
    const float* w5 = (const float*)d_in[13];
    const float* b5 = (const float*)d_in[14];
    const float* wdap = (const float*)d_in[15];
    float* outp = (float*)d_out;

    // workspace (fixed):
    //  wsw0 @0 (110592) | wsw0a @110592 (110592) | wsw1 @221184 (393216)
    //  wsw2 @614400 (294912) | wsw3 @909312 (147456) | wswd @1056768 (65536)
    //  f1n @1122304 (786432) | part0(bf16) @1908736 (1179648) | cost @3088384 (1204224)
    //  f2n @4292608 (786432) | fixed_end = 5079040
    char* ws = (char*)d_ws;
    bf16* wsw0 = (bf16*)(ws + 0);
    bf16* wsw0a = (bf16*)(ws + 110592);
    bf16* wsw1 = (bf16*)(ws + 221184);
    bf16* wsw2 = (bf16*)(ws + 614400);
    bf16* wsw3 = (bf16*)(ws + 909312);
    bf16* wswd = (bf16*)(ws + 1056768);
    bf16* f1n = (bf16*)(ws + 1122304);
    bf16* part0 = (bf16*)(ws + 1908736);
    float* cost = (float*)(ws + 3088384);
    bf16* f2n = (bf16*)(ws + 4292608);
    const size_t fixed_end = 5079040;

    const int cand[7] = {98, 49, 25, 14, 7, 2, 1};
    int nb = 0;
    for (int i = 0; i < 7; ++i) {
        if (fixed_end + (size_t)983040 * cand[i] <= ws_size) { nb = cand[i]; break; }
    }
    if (nb == 0) {
        float val = 10000.f + (float)(ws_size >> 20);
        sentinel_k<<<dim3((out_size + 255) / 256), 256, 0, stream>>>(outp, out_size, val);
        return;
    }
    char* regA = ws + fixed_end;
    char* regB = regA + (size_t)393216 * nb;
    bf16* f2w = (bf16*)regA;  // (nb,48,64,64)
    bf16* x1 = (bf16*)regA;   // (nb,24,32,128)
    bf16* x3 = (bf16*)regA;   // (nb,24,32,64)
    bf16* x0p = (bf16*)regB;  // (nb,24,32,384) parity-packed
    bf16* x2 = (bf16*)regB;   // (nb,24,32,128)
    bf16* xd = (bf16*)regB;   // (nb,48,64,32)

    // prologue: 1 merged launch + part0
    prologue_k<<<dim3(5265), 256, 0, stream>>>(w0, w1, w2, w3, wd, feat1, feat2, wsw0, wsw0a,
                                               wsw1, wsw2, wsw3, wswd, f1n, f2n);
    // part0 = conv3x3(f1n, w0[:,:64]) + b0 -> bf16 NHWC (2,48,64,96), no ReLU
    conv_px4<64, 96, 96, 48, 64, 2, 9, 3, -1, -1, 0, 4>
        <<<dim3(24, 1, 2), 256, 0, stream>>>(f1n, wsw0a, b0, nullptr, part0, 0);

    for (int s = 0; s < 98; s += nb) {
        int cnt = (98 - s < nb) ? (98 - s) : nb;
        warp_kernel<<<dim3(cnt * 96), 256, 0, stream>>>(f2n, coords, f2w, s, cnt);
        // conv0: IC=64 taps3x3 OC=96, base=part0(bf16), parity-pack out
        conv_px4<64, 96, 96, 48, 64, 2, 9, 3, -1, -1, 1, 1>
            <<<dim3(24, 1, cnt), 256, 0, stream>>>(f2w, wsw0, nullptr, part0, x0p, s);
        // conv1: IC=384 taps{-1,0}^2 OC=128, oc split 2
        conv_px4<384, 128, 64, 24, 32, 4, 4, 2, -1, -1, 0, 0>
            <<<dim3(6, 2, cnt), 256, 0, stream>>>(x0p, wsw1, b1, nullptr, x1, s);
        // conv2: IC=128 taps3x3 OC=128, oc split 2
        conv_px4<128, 128, 64, 24, 32, 4, 9, 3, -1, -1, 0, 0>
            <<<dim3(6, 2, cnt), 256, 0, stream>>>(x1, wsw2, b2, nullptr, x2, s);
        // conv3: IC=128 taps3x3 OC=64, no oc split (NfT=4)
        conv_px4<128, 64, 64, 24, 32, 4, 9, 3, -1, -1, 0, 0>
            <<<dim3(6, 1, cnt), 256, 0, stream>>>(x2, wsw3, b3, nullptr, x3, s);
        // deconv: merged 4 classes (wave=class)
        deconv_c4<<<dim3(6, cnt), 256, 0, stream>>>(x3, wswd, bdc, xd);
        // conv5
        conv5_k<<<dim3(cnt * 12), 256, 0, stream>>>(xd, w5, b5, cost, s, cnt);
    }

    dap_flow_w<<<dim3(1536), 256, 0, stream>>>(cost, wdap, coords, outp);
}